// Round 9
// baseline (75133.508 us; speedup 1.0000x reference)
//
#include <hip/hip_runtime.h>
#include <stdint.h>
#include <cstdio>

typedef unsigned short u16;
typedef __attribute__((ext_vector_type(8))) __bf16 bf16x8;
typedef __attribute__((ext_vector_type(4))) float f32x4;
typedef __attribute__((ext_vector_type(4))) int i32x4;

#define AGENT __HIP_MEMORY_SCOPE_AGENT

__device__ __forceinline__ float bf2f(u16 u) {
  unsigned int x = ((unsigned int)u) << 16;
  return __builtin_bit_cast(float, x);
}
__device__ __forceinline__ u16 f2bf(float f) {
  unsigned int x = __builtin_bit_cast(unsigned int, f);
  unsigned int r = (x + 0x7fffu + ((x >> 16) & 1u)) >> 16;
  return (u16)r;
}
__device__ __forceinline__ float sigm(float x) { return 1.f / (1.f + __expf(-x)); }
__device__ __forceinline__ float tanh_f(float x) { return 1.f - 2.f / (__expf(2.f * x) + 1.f); }

__device__ __forceinline__ bool tags_ok(i32x4 v0, i32x4 v1, int expect) {
  bool ok = true;
#pragma unroll
  for (int j = 0; j < 4; ++j)
    ok = ok && ((v0[j] & 0xffff) == expect) && ((v1[j] & 0xffff) == expect);
  return ok;
}

// ---------- fp32 -> bf16 convert (x) ----------
__global__ __launch_bounds__(256) void k_cvt(const float* __restrict__ in, u16* __restrict__ out, int n4) {
  int i = blockIdx.x * 256 + threadIdx.x;
  if (i >= n4) return;
  float4 f = ((const float4*)in)[i];
  ushort4 o;
  o.x = f2bf(f.x); o.y = f2bf(f.y); o.z = f2bf(f.z); o.w = f2bf(f.w);
  ((ushort4*)out)[i] = o;
}

// ---------- pack Wx [768][3072] -> B-fragment order [nt=192][kt=24][lane=64][j=8] ----------
__global__ __launch_bounds__(256) void k_pack_wx(const float* __restrict__ Wx, u16* __restrict__ Bp) {
  int idx = blockIdx.x * 256 + threadIdx.x;
  if (idx >= 2359296) return;
  int j = idx & 7;
  int l = (idx >> 3) & 63;
  int t = idx >> 9;          // nt*24 + kt
  int kt = t % 24, nt = t / 24;
  int k = kt * 32 + (l >> 4) * 8 + j;
  int n = nt * 16 + (l & 15);
  Bp[idx] = f2bf(Wx[(size_t)k * 3072 + n]);
}

// ---------- pack Wh -> per-member slices [w=32][nt=6][kt=24][lane=64][j=8] ----------
// col order within 16-col tile: cc = 4*vi + q (vi = unit-in-wave 0..3, q = gate 0..3)
__global__ __launch_bounds__(256) void k_pack_wh(const float* __restrict__ Wh, u16* __restrict__ Wp) {
  int idx = blockIdx.x * 256 + threadIdx.x;
  if (idx >= 2359296) return;
  int j = idx & 7;
  int l = (idx >> 3) & 63;
  int t = idx >> 9;          // w*144 + nt*24 + kt
  int kt = t % 24;
  int tmp = t / 24;          // w*6 + nt
  int nt = tmp % 6, w = tmp / 6;
  int k = kt * 32 + (l >> 4) * 8 + j;
  int cc = l & 15;
  int vi = cc >> 2, q = cc & 3;
  int gcol = q * 768 + w * 24 + nt * 4 + vi;
  Wp[idx] = f2bf(Wh[(size_t)k * 3072 + gcol]);
}

// ---------- GEMM: C[16384][3072] bf16 = A[16384][768] bf16 @ Bp(packed) ----------
__global__ __launch_bounds__(256, 2) void k_gemm(const u16* __restrict__ A, const u16* __restrict__ Bp,
                                                 u16* __restrict__ C) {
  const int bid = blockIdx.x;
  const int bm = bid & 127, bn = bid >> 7;   // 128 x 24
  const int tid = threadIdx.x, lane = tid & 63, wv = tid >> 6;
  const int wm = wv >> 1, wn = wv & 1;
  const int row0 = bm * 128 + wm * 64;
  const int col0 = bn * 128 + wn * 64;
  const int rlo = lane & 15, rhi = lane >> 4;
  f32x4 acc[4][4] = {};
  const u16* Ab = A + (size_t)(row0 + rlo) * 768 + rhi * 8;
  const u16* Bb = Bp + ((size_t)(bn * 8 + wn * 4) * 24 * 64 + lane) * 8;
#pragma unroll 2
  for (int kt = 0; kt < 24; ++kt) {
    bf16x8 a[4], b[4];
#pragma unroll
    for (int i = 0; i < 4; ++i) a[i] = *(const bf16x8*)(Ab + (size_t)i * 16 * 768 + kt * 32);
#pragma unroll
    for (int j = 0; j < 4; ++j) b[j] = *(const bf16x8*)(Bb + (size_t)j * 24 * 64 * 8 + (size_t)kt * 64 * 8);
#pragma unroll
    for (int i = 0; i < 4; ++i)
#pragma unroll
      for (int j = 0; j < 4; ++j)
        acc[i][j] = __builtin_amdgcn_mfma_f32_16x16x32_bf16(a[i], b[j], acc[i][j], 0, 0, 0);
  }
#pragma unroll
  for (int i = 0; i < 4; ++i)
#pragma unroll
    for (int j = 0; j < 4; ++j)
#pragma unroll
      for (int r = 0; r < 4; ++r) {
        int row = row0 + i * 16 + rhi * 4 + r;
        int col = col0 + j * 16 + rlo;
        C[(size_t)row * 3072 + col] = f2bf(acc[i][j][r]);
      }
}

// ---------- persistent LSTM recurrence, adaptive XCD-local sync ----------
// 256 WGs x 384 threads (6 waves). Logical groups: g = wid&7 (4 seqs), member w = wid>>3 (24 units).
// Producers dual-publish tagged h: plain store -> own-XCD L2 (fast path, speculative) AND
// agent-scope store -> LLC (ground truth). Steps 2..17 poll LLC (proven R8 loop) + trailing
// probe of the local copy; a cross-XCD peer's line, once primed in this L2, MUST read stale on
// the same-parity revisit (no cross-XCD invalidation) -> training fails -> stay on LLC loop.
// If all 16 probes pass (WG-uniform), steps 18+ poll the local buffer with sc0 (pure L2) with
// a 1/256-iteration LLC escalation for liveness. Correctness never depends on placement.
__global__ __launch_bounds__(384) void k_rec(
    const u16* __restrict__ xg,    // [16384][3072] bf16, m = seq*512 + t
    const u16* __restrict__ Whp,   // [32][6][24][64][8] packed bf16
    const float* __restrict__ bias,
    int* hbuf,                     // [8 groups][2][3072] tagged dwords, LLC copy (zeroed)
    int* hloc,                     // [8 groups][2][3072] tagged dwords, local-L2 copy (zeroed)
    u16* __restrict__ hout_bf,     // layer 0 out (bf16) or null
    float* __restrict__ hout_f,    // layer 1 out (fp32) or null
    int layer) {
  __shared__ __align__(16) int hlds[2][4 * 400];  // double-buffered h_{t-1}[4 seq][768]
  __shared__ __align__(16) float wlds[6][68];     // per-wave 16x4 gate transpose scratch
  __shared__ int s_localok;

  const int wid = blockIdx.x, g = wid & 7, w = wid >> 3;
  const int tid = threadIdx.x, lane = tid & 63, wv = tid >> 6;
  if (tid == 0) s_localok = 1;

  // ---- Wh fragments -> registers (static indices) ----
  bf16x8 bregE[12], bregO[12];
  {
    const u16* bp = Whp + (((size_t)(w * 6 + wv) * 24) * 64 + lane) * 8;
#pragma unroll
    for (int kk = 0; kk < 12; ++kk) {
      bregE[kk] = *(const bf16x8*)(bp + (size_t)(2 * kk) * 512);
      bregO[kk] = *(const bf16x8*)(bp + (size_t)(2 * kk + 1) * 512);
    }
  }

  // ---- cell role: lanes 0-15 of each wave own cell (seq r, unit vi) ----
  const bool cellt = lane < 16;
  const int vi = lane & 3, r = (lane >> 2) & 3;
  const int unit = w * 24 + wv * 4 + vi;
  const int seq = g * 4 + r;
  float bv0 = 0, bv1 = 0, bv2 = 0, bv3 = 0, xv0 = 0, xv1 = 0, xv2 = 0, xv3 = 0;
  if (cellt) {
    bv0 = bias[unit]; bv1 = bias[768 + unit]; bv2 = bias[1536 + unit]; bv3 = bias[2304 + unit];
    const u16* xr = xg + (size_t)seq * 512 * 3072;
    xv0 = bf2f(xr[unit]); xv1 = bf2f(xr[768 + unit]);
    xv2 = bf2f(xr[1536 + unit]); xv3 = bf2f(xr[2304 + unit]);
  }
  float cst = 0.f;
  const int sl = (lane & 15) < 4 ? (lane & 15) : 3;      // A-frag row (pad rows clamped)
  const int abase = sl * 400 + (lane >> 4) * 4;          // A-frag dword base within buffer
  const int c = tid;                                     // poll chunk id (8 dwords)
  const int hrow = c / 96, hcol = (c % 96) * 4;          // staged int4 slot
  int guard = 0;
  bool mode_local = false;
  bool localok = true;

  __syncthreads();

  for (int t = 0; t < 512; ++t) {
    int* hb = hlds[t & 1];
    const int expect = t;  // tag written by step t-1 producers (t=0: zeroed buffer)
    int* srcG = hbuf + (size_t)(g * 2 + (t & 1)) * 3072;
    int* srcL = hloc + (size_t)(g * 2 + (t & 1)) * 3072;
    const int* gp0 = srcG + 8 * c;
    const int* gp1 = srcG + 8 * c + 4;
    const int* lp0 = srcL + 8 * c;
    const int* lp1 = srcL + 8 * c + 4;
    i32x4 v0, v1;

    if (mode_local) {
      // ---- fast path: poll own-XCD L2 copy only (sc0), LLC escalation every 256 iters ----
      int it = 0;
      for (;;) {
        asm volatile("global_load_dwordx4 %0, %2, off sc0\n\t"
                     "global_load_dwordx4 %1, %3, off sc0\n\t"
                     "s_waitcnt vmcnt(0)"
                     : "=&v"(v0), "=&v"(v1)
                     : "v"(lp0), "v"(lp1)
                     : "memory");
        if (tags_ok(v0, v1, expect)) break;
        if ((it & 255) == 255) {  // liveness escalation: ground-truth LLC copy
          i32x4 w0, w1;
          asm volatile("global_load_dwordx4 %0, %2, off sc0 sc1\n\t"
                       "global_load_dwordx4 %1, %3, off sc0 sc1\n\t"
                       "s_waitcnt vmcnt(0)"
                       : "=&v"(w0), "=&v"(w1)
                       : "v"(gp0), "v"(gp1)
                       : "memory");
          if (tags_ok(w0, w1, expect)) { v0 = w0; v1 = w1; break; }
        }
        ++it;
        if (++guard > (1 << 22)) break;
      }
    } else {
      // ---- proven LLC merged poll+fetch (R8) ----
      for (;;) {
        asm volatile("global_load_dwordx4 %0, %2, off sc0 sc1\n\t"
                     "global_load_dwordx4 %1, %3, off sc0 sc1\n\t"
                     "s_waitcnt vmcnt(0)"
                     : "=&v"(v0), "=&v"(v1)
                     : "v"(gp0), "v"(gp1)
                     : "memory");
        if (tags_ok(v0, v1, expect) || ++guard > (1 << 22)) break;
      }
      // training probe (t=2..17): does the local-L2 copy cohere with this group's producers?
      // Probe also primes this L2 with the line, forcing the stale-hit test on the next
      // same-parity revisit for any cross-XCD peer.
      if (t >= 2 && t < 18) {
        i32x4 w0, w1;
        asm volatile("global_load_dwordx4 %0, %2, off sc0\n\t"
                     "global_load_dwordx4 %1, %3, off sc0\n\t"
                     "s_waitcnt vmcnt(0)"
                     : "=&v"(w0), "=&v"(w1)
                     : "v"(lp0), "v"(lp1)
                     : "memory");
        localok = localok && tags_ok(w0, w1, expect);
        if (t == 17 && !localok) s_localok = 0;
      }
    }

    // stage packed bf16 pairs into hlds[t&1]
    {
      int4 pk;
      pk.x = (int)(((unsigned)v0[0] >> 16) | ((unsigned)v0[1] & 0xffff0000u));
      pk.y = (int)(((unsigned)v0[2] >> 16) | ((unsigned)v0[3] & 0xffff0000u));
      pk.z = (int)(((unsigned)v1[0] >> 16) | ((unsigned)v1[1] & 0xffff0000u));
      pk.w = (int)(((unsigned)v1[2] >> 16) | ((unsigned)v1[3] & 0xffff0000u));
      *(int4*)&hb[hrow * 400 + hcol] = pk;
    }
    __syncthreads();  // hlds[t&1] ready (also fences next step's staging vs MFMA(t-1))
    if (t == 17) mode_local = (s_localok != 0);  // WG-uniform decision, applies from t=18

    // ---- MFMA: gates[4 seq][16 cols of wave tile], 4 independent chains of 6 ----
    f32x4 a0 = {0, 0, 0, 0}, a1 = {0, 0, 0, 0}, a2 = {0, 0, 0, 0}, a3 = {0, 0, 0, 0};
#pragma unroll
    for (int kk = 0; kk < 12; kk += 2) {
      bf16x8 e0 = *(const bf16x8*)(hb + abase + (2 * kk) * 16);
      bf16x8 o0 = *(const bf16x8*)(hb + abase + (2 * kk + 1) * 16);
      bf16x8 e1 = *(const bf16x8*)(hb + abase + (2 * kk + 2) * 16);
      bf16x8 o1 = *(const bf16x8*)(hb + abase + (2 * kk + 3) * 16);
      a0 = __builtin_amdgcn_mfma_f32_16x16x32_bf16(e0, bregE[kk], a0, 0, 0, 0);
      a1 = __builtin_amdgcn_mfma_f32_16x16x32_bf16(o0, bregO[kk], a1, 0, 0, 0);
      a2 = __builtin_amdgcn_mfma_f32_16x16x32_bf16(e1, bregE[kk + 1], a2, 0, 0, 0);
      a3 = __builtin_amdgcn_mfma_f32_16x16x32_bf16(o1, bregO[kk + 1], a3, 0, 0, 0);
    }
    a0 = (a0 + a2) + (a1 + a3);

    // ---- wave-local 16x4 transpose -> cell lanes (no WG barrier) ----
    if (cellt) {
#pragma unroll
      for (int rr = 0; rr < 4; ++rr) wlds[wv][rr * 16 + lane] = a0[rr];
    }
    asm volatile("s_waitcnt lgkmcnt(0)" ::: "memory");
    if (cellt) {
      f32x4 tr = *(const f32x4*)&wlds[wv][r * 16 + vi * 4];  // gates i,f,g,o
      float p0g = xv0 + tr[0] + bv0;
      float p1g = xv1 + tr[1] + bv1;
      float p2g = xv2 + tr[2] + bv2;
      float p3g = xv3 + tr[3] + bv3;
      float ig = sigm(p0g), fg = sigm(p1g), gg = tanh_f(p2g), og = sigm(p3g);
      cst = fg * cst + ig * gg;
      float h = og * tanh_f(cst);
      // dual-publish tagged h (both fire-and-forget; dword atomicity self-validates)
      size_t off = (size_t)(g * 2 + ((t + 1) & 1)) * 3072 + r * 768 + unit;
      int val = (int)(((unsigned)f2bf(h) << 16) | (unsigned)(t + 1));
      int* dstL = hloc + off;
      asm volatile("global_store_dword %0, %1, off" :: "v"(dstL), "v"(val) : "memory");
      __hip_atomic_store(hbuf + off, val, __ATOMIC_RELAXED, AGENT);
      // off the critical path: output store + next-step xg prefetch
      size_t o = ((size_t)seq * 512 + t) * 768 + unit;
      if (layer == 0) hout_bf[o] = f2bf(h); else hout_f[o] = h;
      if (t + 1 < 512) {
        const u16* xr = xg + ((size_t)seq * 512 + t + 1) * 3072;
        xv0 = bf2f(xr[unit]); xv1 = bf2f(xr[768 + unit]);
        xv2 = bf2f(xr[1536 + unit]); xv3 = bf2f(xr[2304 + unit]);
      }
    }
  }
}

// ---------- LayerNorm (in-place safe) ----------
__global__ __launch_bounds__(256) void k_ln(const float* __restrict__ in, const float* __restrict__ sc,
                                            const float* __restrict__ bi, float* __restrict__ out) {
  const int row = blockIdx.x, tid = threadIdx.x;
  const float* x = in + (size_t)row * 768;
  float v0 = x[tid], v1 = x[tid + 256], v2 = x[tid + 512];
  float s = v0 + v1 + v2;
  float s2 = v0 * v0 + v1 * v1 + v2 * v2;
#pragma unroll
  for (int off = 32; off >= 1; off >>= 1) {
    s += __shfl_xor(s, off);
    s2 += __shfl_xor(s2, off);
  }
  __shared__ float red[8];
  const int wv = tid >> 6;
  if ((tid & 63) == 0) { red[wv] = s; red[4 + wv] = s2; }
  __syncthreads();
  s = red[0] + red[1] + red[2] + red[3];
  s2 = red[4] + red[5] + red[6] + red[7];
  float mean = s * (1.f / 768.f);
  float var = s2 * (1.f / 768.f) - mean * mean;
  float rs = rsqrtf(var + 1e-6f);
  float* o = out + (size_t)row * 768;
  o[tid] = (v0 - mean) * rs * sc[tid] + bi[tid];
  o[tid + 256] = (v1 - mean) * rs * sc[tid + 256] + bi[tid + 256];
  o[tid + 512] = (v2 - mean) * rs * sc[tid + 512] + bi[tid + 512];
}

extern "C" void kernel_launch(void* const* d_in, const int* in_sizes, int n_in,
                              void* d_out, int out_size, void* d_ws, size_t ws_size,
                              hipStream_t stream) {
  const float* x   = (const float*)d_in[0];
  const float* Wx0 = (const float*)d_in[1];
  const float* Wh0 = (const float*)d_in[2];
  const float* b0  = (const float*)d_in[3];
  const float* Wx1 = (const float*)d_in[4];
  const float* Wh1 = (const float*)d_in[5];
  const float* b1  = (const float*)d_in[6];
  const float* lns = (const float*)d_in[7];
  const float* lnb = (const float*)d_in[8];
  float* out = (float*)d_out;

  char* p = (char*)d_ws;
  auto alloc = [&](size_t bytes) {
    char* r = p;
    p += (bytes + 255) & ~(size_t)255;
    return r;
  };
  u16* xg    = (u16*)alloc(16384ull * 3072 * 2);
  u16* xbf   = (u16*)alloc(16384ull * 768 * 2);
  u16* h0bf  = (u16*)alloc(16384ull * 768 * 2);
  u16* Wxp0  = (u16*)alloc(2359296ull * 2);
  u16* Wxp1  = (u16*)alloc(2359296ull * 2);
  u16* Whp0  = (u16*)alloc(2359296ull * 2);
  u16* Whp1  = (u16*)alloc(2359296ull * 2);
  char* sync0 = alloc(196608ull * 4);   // hbuf0/1 (LLC), hloc0/1 (XCD-local)
  int* hbuf0 = (int*)sync0;
  int* hbuf1 = (int*)(sync0 + 196608);
  int* hloc0 = (int*)(sync0 + 196608ull * 2);
  int* hloc1 = (int*)(sync0 + 196608ull * 3);

  if ((size_t)(p - (char*)d_ws) > ws_size) {
    fprintf(stderr, "kernel_launch: ws too small: need %zu have %zu\n",
            (size_t)(p - (char*)d_ws), ws_size);
    return;
  }

  hipMemsetAsync(sync0, 0, 196608ull * 4, stream);
  k_cvt<<<12288, 256, 0, stream>>>(x, xbf, 3145728);
  k_pack_wx<<<9216, 256, 0, stream>>>(Wx0, Wxp0);
  k_pack_wx<<<9216, 256, 0, stream>>>(Wx1, Wxp1);
  k_pack_wh<<<9216, 256, 0, stream>>>(Wh0, Whp0);
  k_pack_wh<<<9216, 256, 0, stream>>>(Wh1, Whp1);

  k_gemm<<<3072, 256, 0, stream>>>(xbf, Wxp0, xg);
  k_rec<<<256, 384, 0, stream>>>(xg, Whp0, b0, hbuf0, hloc0, h0bf, nullptr, 0);
  k_gemm<<<3072, 256, 0, stream>>>(h0bf, Wxp1, xg);
  k_rec<<<256, 384, 0, stream>>>(xg, Whp1, b1, hbuf1, hloc1, nullptr, (float*)d_out, 1);
  k_ln<<<16384, 256, 0, stream>>>((const float*)d_out, lns, lnb, out);
}

// Round 10
// 3475.464 us; speedup vs baseline: 21.6183x; 21.6183x over previous
//
#include <hip/hip_runtime.h>
#include <stdint.h>
#include <cstdio>

typedef unsigned short u16;
typedef __attribute__((ext_vector_type(8))) __bf16 bf16x8;
typedef __attribute__((ext_vector_type(4))) float f32x4;
typedef __attribute__((ext_vector_type(4))) int i32x4;

#define AGENT __HIP_MEMORY_SCOPE_AGENT

__device__ __forceinline__ float bf2f(u16 u) {
  unsigned int x = ((unsigned int)u) << 16;
  return __builtin_bit_cast(float, x);
}
__device__ __forceinline__ u16 f2bf(float f) {
  unsigned int x = __builtin_bit_cast(unsigned int, f);
  unsigned int r = (x + 0x7fffu + ((x >> 16) & 1u)) >> 16;
  return (u16)r;
}
__device__ __forceinline__ float sigm(float x) { return 1.f / (1.f + __expf(-x)); }
__device__ __forceinline__ float tanh_f(float x) { return 1.f - 2.f / (__expf(2.f * x) + 1.f); }

// ---------- fp32 -> bf16 convert (x) ----------
__global__ __launch_bounds__(256) void k_cvt(const float* __restrict__ in, u16* __restrict__ out, int n4) {
  int i = blockIdx.x * 256 + threadIdx.x;
  if (i >= n4) return;
  float4 f = ((const float4*)in)[i];
  ushort4 o;
  o.x = f2bf(f.x); o.y = f2bf(f.y); o.z = f2bf(f.z); o.w = f2bf(f.w);
  ((ushort4*)out)[i] = o;
}

// ---------- pack Wx [768][3072] -> B-fragment order [nt=192][kt=24][lane=64][j=8] ----------
__global__ __launch_bounds__(256) void k_pack_wx(const float* __restrict__ Wx, u16* __restrict__ Bp) {
  int idx = blockIdx.x * 256 + threadIdx.x;
  if (idx >= 2359296) return;
  int j = idx & 7;
  int l = (idx >> 3) & 63;
  int t = idx >> 9;          // nt*24 + kt
  int kt = t % 24, nt = t / 24;
  int k = kt * 32 + (l >> 4) * 8 + j;
  int n = nt * 16 + (l & 15);
  Bp[idx] = f2bf(Wx[(size_t)k * 3072 + n]);
}

// ---------- pack Wh -> per-member slices [w=16][nt=12][kt=24][lane=64][j=8] ----------
// member w owns 48 units; within a 16-col tile, col cc = 4*vi + q (vi=unit-in-wave, q=gate)
// unit = w*48 + nt*4 + vi ; gcol = q*768 + unit
__global__ __launch_bounds__(256) void k_pack_wh(const float* __restrict__ Wh, u16* __restrict__ Wp) {
  int idx = blockIdx.x * 256 + threadIdx.x;
  if (idx >= 2359296) return;
  int j = idx & 7;
  int l = (idx >> 3) & 63;
  int t = idx >> 9;          // w*288 + nt*24 + kt
  int kt = t % 24;
  int tmp = t / 24;          // w*12 + nt
  int nt = tmp % 12, w = tmp / 12;
  int k = kt * 32 + (l >> 4) * 8 + j;
  int cc = l & 15;
  int vi = cc >> 2, q = cc & 3;
  int gcol = q * 768 + w * 48 + nt * 4 + vi;
  Wp[idx] = f2bf(Wh[(size_t)k * 3072 + gcol]);
}

// ---------- GEMM: C[16384][3072] bf16 = A[16384][768] bf16 @ Bp(packed) ----------
__global__ __launch_bounds__(256, 2) void k_gemm(const u16* __restrict__ A, const u16* __restrict__ Bp,
                                                 u16* __restrict__ C) {
  const int bid = blockIdx.x;
  const int bm = bid & 127, bn = bid >> 7;   // 128 x 24
  const int tid = threadIdx.x, lane = tid & 63, wv = tid >> 6;
  const int wm = wv >> 1, wn = wv & 1;
  const int row0 = bm * 128 + wm * 64;
  const int col0 = bn * 128 + wn * 64;
  const int rlo = lane & 15, rhi = lane >> 4;
  f32x4 acc[4][4] = {};
  const u16* Ab = A + (size_t)(row0 + rlo) * 768 + rhi * 8;
  const u16* Bb = Bp + ((size_t)(bn * 8 + wn * 4) * 24 * 64 + lane) * 8;
#pragma unroll 2
  for (int kt = 0; kt < 24; ++kt) {
    bf16x8 a[4], b[4];
#pragma unroll
    for (int i = 0; i < 4; ++i) a[i] = *(const bf16x8*)(Ab + (size_t)i * 16 * 768 + kt * 32);
#pragma unroll
    for (int j = 0; j < 4; ++j) b[j] = *(const bf16x8*)(Bb + (size_t)j * 24 * 64 * 8 + (size_t)kt * 64 * 8);
#pragma unroll
    for (int i = 0; i < 4; ++i)
#pragma unroll
      for (int j = 0; j < 4; ++j)
        acc[i][j] = __builtin_amdgcn_mfma_f32_16x16x32_bf16(a[i], b[j], acc[i][j], 0, 0, 0);
  }
#pragma unroll
  for (int i = 0; i < 4; ++i)
#pragma unroll
    for (int j = 0; j < 4; ++j)
#pragma unroll
      for (int r = 0; r < 4; ++r) {
        int row = row0 + i * 16 + rhi * 4 + r;
        int col = col0 + j * 16 + rlo;
        C[(size_t)row * 3072 + col] = f2bf(acc[i][j][r]);
      }
}

// ---------- persistent LSTM recurrence ----------
// 128 WGs x 768 threads (12 waves). Logical groups: g = wid&7 (4 seqs), member w = wid>>3
// (0..15, 48 units each). Wave wv (0..11) owns one 16-col tile = 4 gates x 4 units.
// Per step: merged poll+fetch (ONE dwordx4/thread) of tagged h_{t-1} -> stage hlds[t&1] ->
// one __syncthreads -> MFMA (4 indep chains) -> wave-local 16x4 transpose -> cell math ->
// fire-and-forget tagged publish (bf16_h<<16 | t+1), double-buffered by t parity.
// Same proven LLC protocol as R6/R8; only the decomposition (16 members, 16B polls) changed.
__global__ __launch_bounds__(768, 3) void k_rec(
    const u16* __restrict__ xg,    // [16384][3072] bf16, m = seq*512 + t
    const u16* __restrict__ Whp,   // [16][12][24][64][8] packed bf16
    const float* __restrict__ bias,
    int* hbuf,                     // [8 groups][2][3072] tagged dwords (zeroed)
    u16* __restrict__ hout_bf,     // layer 0 out (bf16) or null
    float* __restrict__ hout_f,    // layer 1 out (fp32) or null
    int layer) {
  __shared__ __align__(16) int hlds[2][4 * 400];  // double-buffered h_{t-1}[4 seq][768]
  __shared__ __align__(16) float wlds[12][68];    // per-wave 16x4 gate transpose scratch

  const int wid = blockIdx.x, g = wid & 7, w = wid >> 3;
  const int tid = threadIdx.x, lane = tid & 63, wv = tid >> 6;

  // ---- Wh fragments -> registers (static indices) ----
  bf16x8 bregE[12], bregO[12];
  {
    const u16* bp = Whp + (((size_t)(w * 12 + wv) * 24) * 64 + lane) * 8;
#pragma unroll
    for (int kk = 0; kk < 12; ++kk) {
      bregE[kk] = *(const bf16x8*)(bp + (size_t)(2 * kk) * 512);
      bregO[kk] = *(const bf16x8*)(bp + (size_t)(2 * kk + 1) * 512);
    }
  }

  // ---- cell role: lanes 0-15 of each wave own cell (seq r, unit vi) ----
  const bool cellt = lane < 16;
  const int vi = lane & 3, r = (lane >> 2) & 3;
  const int unit = w * 48 + wv * 4 + vi;
  const int seq = g * 4 + r;
  float bv0 = 0, bv1 = 0, bv2 = 0, bv3 = 0, xv0 = 0, xv1 = 0, xv2 = 0, xv3 = 0;
  if (cellt) {
    bv0 = bias[unit]; bv1 = bias[768 + unit]; bv2 = bias[1536 + unit]; bv3 = bias[2304 + unit];
    const u16* xr = xg + (size_t)seq * 512 * 3072;
    xv0 = bf2f(xr[unit]); xv1 = bf2f(xr[768 + unit]);
    xv2 = bf2f(xr[1536 + unit]); xv3 = bf2f(xr[2304 + unit]);
  }
  float cst = 0.f;
  const int sl = (lane & 15) < 4 ? (lane & 15) : 3;      // A-frag row (pad rows clamped)
  const int abase = sl * 400 + (lane >> 4) * 4;          // A-frag dword base within buffer
  const int c = tid;                                     // poll chunk id (4 dwords)
  const int hrow = c / 192, hcol = (c % 192) * 2;        // staged int2 slot
  int guard = 0;

  __syncthreads();

  for (int t = 0; t < 512; ++t) {
    int* hb = hlds[t & 1];
    // ---- merged poll+fetch of h_{t-1}: ONE tagged dwordx4 IS the poll (1 RT) ----
    const int expect = t;  // tag written by step t-1 producers (t=0: zeroed buffer)
    int* src = hbuf + (size_t)(g * 2 + (t & 1)) * 3072;
    const int* p0 = src + 4 * c;
    i32x4 v0;
    for (;;) {
      asm volatile("global_load_dwordx4 %0, %1, off sc0 sc1\n\t"
                   "s_waitcnt vmcnt(0)"
                   : "=&v"(v0)
                   : "v"(p0)
                   : "memory");
      bool ok = true;
#pragma unroll
      for (int j = 0; j < 4; ++j) ok = ok && ((v0[j] & 0xffff) == expect);
      if (ok || ++guard > (1 << 22)) break;
    }
    // stage packed bf16 pairs into hlds[t&1]
    {
      int2 pk;
      pk.x = (int)(((unsigned)v0[0] >> 16) | ((unsigned)v0[1] & 0xffff0000u));
      pk.y = (int)(((unsigned)v0[2] >> 16) | ((unsigned)v0[3] & 0xffff0000u));
      *(int2*)&hb[hrow * 400 + hcol] = pk;
    }
    __syncthreads();  // hlds[t&1] ready (also fences next step's staging vs MFMA(t-1))

    // ---- MFMA: gates[4 seq][16 cols of wave tile], 4 independent chains of 6 ----
    f32x4 a0 = {0, 0, 0, 0}, a1 = {0, 0, 0, 0}, a2 = {0, 0, 0, 0}, a3 = {0, 0, 0, 0};
#pragma unroll
    for (int kk = 0; kk < 12; kk += 2) {
      bf16x8 e0 = *(const bf16x8*)(hb + abase + (2 * kk) * 16);
      bf16x8 o0 = *(const bf16x8*)(hb + abase + (2 * kk + 1) * 16);
      bf16x8 e1 = *(const bf16x8*)(hb + abase + (2 * kk + 2) * 16);
      bf16x8 o1 = *(const bf16x8*)(hb + abase + (2 * kk + 3) * 16);
      a0 = __builtin_amdgcn_mfma_f32_16x16x32_bf16(e0, bregE[kk], a0, 0, 0, 0);
      a1 = __builtin_amdgcn_mfma_f32_16x16x32_bf16(o0, bregO[kk], a1, 0, 0, 0);
      a2 = __builtin_amdgcn_mfma_f32_16x16x32_bf16(e1, bregE[kk + 1], a2, 0, 0, 0);
      a3 = __builtin_amdgcn_mfma_f32_16x16x32_bf16(o1, bregO[kk + 1], a3, 0, 0, 0);
    }
    a0 = (a0 + a2) + (a1 + a3);

    // ---- wave-local 16x4 transpose -> cell lanes (no WG barrier) ----
    if (cellt) {
#pragma unroll
      for (int rr = 0; rr < 4; ++rr) wlds[wv][rr * 16 + lane] = a0[rr];
    }
    asm volatile("s_waitcnt lgkmcnt(0)" ::: "memory");
    if (cellt) {
      f32x4 tr = *(const f32x4*)&wlds[wv][r * 16 + vi * 4];  // gates i,f,g,o
      float p0g = xv0 + tr[0] + bv0;
      float p1g = xv1 + tr[1] + bv1;
      float p2g = xv2 + tr[2] + bv2;
      float p3g = xv3 + tr[3] + bv3;
      float ig = sigm(p0g), fg = sigm(p1g), gg = tanh_f(p2g), og = sigm(p3g);
      cst = fg * cst + ig * gg;
      float h = og * tanh_f(cst);
      // publish tagged h (fire-and-forget; dword atomicity makes it self-validating)
      int* dst = hbuf + (size_t)(g * 2 + ((t + 1) & 1)) * 3072 + r * 768 + unit;
      int val = (int)(((unsigned)f2bf(h) << 16) | (unsigned)(t + 1));
      __hip_atomic_store(dst, val, __ATOMIC_RELAXED, AGENT);
      // off the critical path: output store + next-step xg prefetch
      size_t o = ((size_t)seq * 512 + t) * 768 + unit;
      if (layer == 0) hout_bf[o] = f2bf(h); else hout_f[o] = h;
      if (t + 1 < 512) {
        const u16* xr = xg + ((size_t)seq * 512 + t + 1) * 3072;
        xv0 = bf2f(xr[unit]); xv1 = bf2f(xr[768 + unit]);
        xv2 = bf2f(xr[1536 + unit]); xv3 = bf2f(xr[2304 + unit]);
      }
    }
  }
}

// ---------- LayerNorm (in-place safe) ----------
__global__ __launch_bounds__(256) void k_ln(const float* __restrict__ in, const float* __restrict__ sc,
                                            const float* __restrict__ bi, float* __restrict__ out) {
  const int row = blockIdx.x, tid = threadIdx.x;
  const float* x = in + (size_t)row * 768;
  float v0 = x[tid], v1 = x[tid + 256], v2 = x[tid + 512];
  float s = v0 + v1 + v2;
  float s2 = v0 * v0 + v1 * v1 + v2 * v2;
#pragma unroll
  for (int off = 32; off >= 1; off >>= 1) {
    s += __shfl_xor(s, off);
    s2 += __shfl_xor(s2, off);
  }
  __shared__ float red[8];
  const int wv = tid >> 6;
  if ((tid & 63) == 0) { red[wv] = s; red[4 + wv] = s2; }
  __syncthreads();
  s = red[0] + red[1] + red[2] + red[3];
  s2 = red[4] + red[5] + red[6] + red[7];
  float mean = s * (1.f / 768.f);
  float var = s2 * (1.f / 768.f) - mean * mean;
  float rs = rsqrtf(var + 1e-6f);
  float* o = out + (size_t)row * 768;
  o[tid] = (v0 - mean) * rs * sc[tid] + bi[tid];
  o[tid + 256] = (v1 - mean) * rs * sc[tid + 256] + bi[tid + 256];
  o[tid + 512] = (v2 - mean) * rs * sc[tid + 512] + bi[tid + 512];
}

extern "C" void kernel_launch(void* const* d_in, const int* in_sizes, int n_in,
                              void* d_out, int out_size, void* d_ws, size_t ws_size,
                              hipStream_t stream) {
  const float* x   = (const float*)d_in[0];
  const float* Wx0 = (const float*)d_in[1];
  const float* Wh0 = (const float*)d_in[2];
  const float* b0  = (const float*)d_in[3];
  const float* Wx1 = (const float*)d_in[4];
  const float* Wh1 = (const float*)d_in[5];
  const float* b1  = (const float*)d_in[6];
  const float* lns = (const float*)d_in[7];
  const float* lnb = (const float*)d_in[8];
  float* out = (float*)d_out;

  char* p = (char*)d_ws;
  auto alloc = [&](size_t bytes) {
    char* r = p;
    p += (bytes + 255) & ~(size_t)255;
    return r;
  };
  u16* xg    = (u16*)alloc(16384ull * 3072 * 2);
  u16* xbf   = (u16*)alloc(16384ull * 768 * 2);
  u16* h0bf  = (u16*)alloc(16384ull * 768 * 2);
  u16* Wxp0  = (u16*)alloc(2359296ull * 2);
  u16* Wxp1  = (u16*)alloc(2359296ull * 2);
  u16* Whp0  = (u16*)alloc(2359296ull * 2);
  u16* Whp1  = (u16*)alloc(2359296ull * 2);
  char* sync0 = alloc(196608ull * 2);   // hbuf0, hbuf1 (tagged dwords)
  int* hbuf0 = (int*)sync0;
  int* hbuf1 = (int*)(sync0 + 196608);

  if ((size_t)(p - (char*)d_ws) > ws_size) {
    fprintf(stderr, "kernel_launch: ws too small: need %zu have %zu\n",
            (size_t)(p - (char*)d_ws), ws_size);
    return;
  }

  hipMemsetAsync(sync0, 0, 196608ull * 2, stream);
  k_cvt<<<12288, 256, 0, stream>>>(x, xbf, 3145728);
  k_pack_wx<<<9216, 256, 0, stream>>>(Wx0, Wxp0);
  k_pack_wx<<<9216, 256, 0, stream>>>(Wx1, Wxp1);
  k_pack_wh<<<9216, 256, 0, stream>>>(Wh0, Whp0);
  k_pack_wh<<<9216, 256, 0, stream>>>(Wh1, Whp1);

  k_gemm<<<3072, 256, 0, stream>>>(xbf, Wxp0, xg);
  k_rec<<<128, 768, 0, stream>>>(xg, Whp0, b0, hbuf0, h0bf, nullptr, 0);
  k_gemm<<<3072, 256, 0, stream>>>(h0bf, Wxp1, xg);
  k_rec<<<128, 768, 0, stream>>>(xg, Whp1, b1, hbuf1, nullptr, (float*)d_out, 1);
  k_ln<<<16384, 256, 0, stream>>>((const float*)d_out, lns, lnb, out);
}

// Round 11
// 3149.789 us; speedup vs baseline: 23.8535x; 1.1034x over previous
//
#include <hip/hip_runtime.h>
#include <stdint.h>
#include <cstdio>

typedef unsigned short u16;
typedef __attribute__((ext_vector_type(8))) __bf16 bf16x8;
typedef __attribute__((ext_vector_type(4))) float f32x4;
typedef __attribute__((ext_vector_type(4))) int i32x4;

#define AGENT __HIP_MEMORY_SCOPE_AGENT

__device__ __forceinline__ float bf2f(u16 u) {
  unsigned int x = ((unsigned int)u) << 16;
  return __builtin_bit_cast(float, x);
}
__device__ __forceinline__ u16 f2bf(float f) {
  unsigned int x = __builtin_bit_cast(unsigned int, f);
  unsigned int r = (x + 0x7fffu + ((x >> 16) & 1u)) >> 16;
  return (u16)r;
}
__device__ __forceinline__ float sigm(float x) { return 1.f / (1.f + __expf(-x)); }
__device__ __forceinline__ float tanh_f(float x) { return 1.f - 2.f / (__expf(2.f * x) + 1.f); }

__device__ __forceinline__ bool tags_ok(i32x4 v0, i32x4 v1, int expect) {
  bool ok = true;
#pragma unroll
  for (int j = 0; j < 4; ++j)
    ok = ok && ((v0[j] & 0xffff) == expect) && ((v1[j] & 0xffff) == expect);
  return ok;
}

// ---------- fp32 -> bf16 convert (x) ----------
__global__ __launch_bounds__(256) void k_cvt(const float* __restrict__ in, u16* __restrict__ out, int n4) {
  int i = blockIdx.x * 256 + threadIdx.x;
  if (i >= n4) return;
  float4 f = ((const float4*)in)[i];
  ushort4 o;
  o.x = f2bf(f.x); o.y = f2bf(f.y); o.z = f2bf(f.z); o.w = f2bf(f.w);
  ((ushort4*)out)[i] = o;
}

// ---------- pack Wx [768][3072] -> B-fragment order [nt=192][kt=24][lane=64][j=8] ----------
__global__ __launch_bounds__(256) void k_pack_wx(const float* __restrict__ Wx, u16* __restrict__ Bp) {
  int idx = blockIdx.x * 256 + threadIdx.x;
  if (idx >= 2359296) return;
  int j = idx & 7;
  int l = (idx >> 3) & 63;
  int t = idx >> 9;          // nt*24 + kt
  int kt = t % 24, nt = t / 24;
  int k = kt * 32 + (l >> 4) * 8 + j;
  int n = nt * 16 + (l & 15);
  Bp[idx] = f2bf(Wx[(size_t)k * 3072 + n]);
}

// ---------- pack Wh -> per-member slices [w=32][nt=6][kt=24][lane=64][j=8] ----------
// col order within 16-col tile: cc = 4*vi + q (vi = unit-in-wave 0..3, q = gate 0..3)
// Same per-lane (l&15, k) structure serves as the A-operand (rows=cc) in the swapped MFMA.
__global__ __launch_bounds__(256) void k_pack_wh(const float* __restrict__ Wh, u16* __restrict__ Wp) {
  int idx = blockIdx.x * 256 + threadIdx.x;
  if (idx >= 2359296) return;
  int j = idx & 7;
  int l = (idx >> 3) & 63;
  int t = idx >> 9;          // w*144 + nt*24 + kt
  int kt = t % 24;
  int tmp = t / 24;          // w*6 + nt
  int nt = tmp % 6, w = tmp / 6;
  int k = kt * 32 + (l >> 4) * 8 + j;
  int cc = l & 15;
  int vi = cc >> 2, q = cc & 3;
  int gcol = q * 768 + w * 24 + nt * 4 + vi;
  Wp[idx] = f2bf(Wh[(size_t)k * 3072 + gcol]);
}

// ---------- GEMM: C[16384][3072] bf16 = A[16384][768] bf16 @ Bp(packed) ----------
__global__ __launch_bounds__(256, 2) void k_gemm(const u16* __restrict__ A, const u16* __restrict__ Bp,
                                                 u16* __restrict__ C) {
  const int bid = blockIdx.x;
  const int bm = bid & 127, bn = bid >> 7;   // 128 x 24
  const int tid = threadIdx.x, lane = tid & 63, wv = tid >> 6;
  const int wm = wv >> 1, wn = wv & 1;
  const int row0 = bm * 128 + wm * 64;
  const int col0 = bn * 128 + wn * 64;
  const int rlo = lane & 15, rhi = lane >> 4;
  f32x4 acc[4][4] = {};
  const u16* Ab = A + (size_t)(row0 + rlo) * 768 + rhi * 8;
  const u16* Bb = Bp + ((size_t)(bn * 8 + wn * 4) * 24 * 64 + lane) * 8;
#pragma unroll 2
  for (int kt = 0; kt < 24; ++kt) {
    bf16x8 a[4], b[4];
#pragma unroll
    for (int i = 0; i < 4; ++i) a[i] = *(const bf16x8*)(Ab + (size_t)i * 16 * 768 + kt * 32);
#pragma unroll
    for (int j = 0; j < 4; ++j) b[j] = *(const bf16x8*)(Bb + (size_t)j * 24 * 64 * 8 + (size_t)kt * 64 * 8);
#pragma unroll
    for (int i = 0; i < 4; ++i)
#pragma unroll
      for (int j = 0; j < 4; ++j)
        acc[i][j] = __builtin_amdgcn_mfma_f32_16x16x32_bf16(a[i], b[j], acc[i][j], 0, 0, 0);
  }
#pragma unroll
  for (int i = 0; i < 4; ++i)
#pragma unroll
    for (int j = 0; j < 4; ++j)
#pragma unroll
      for (int r = 0; r < 4; ++r) {
        int row = row0 + i * 16 + rhi * 4 + r;
        int col = col0 + j * 16 + rlo;
        C[(size_t)row * 3072 + col] = f2bf(acc[i][j][r]);
      }
}

// ---------- persistent LSTM recurrence ----------
// 256 WGs x 384 threads (6 waves), R8-proven geometry + protocol. Logical groups: g = wid&7
// (4 seqs), member w = wid>>3 (24 units). Wave wv owns one 16-col tile = 4 gates x 4 units.
// SWAPPED MFMA: D = Wfrag(A) x hfrag(B) -> D[cc][seq]; lane 16*vi + r holds all 4 gates
// (regs q=0..3) of cell (seq r, unit vi) -> no gate transpose, cell math straight from acc.
// Poll: 2-deep pipelined tagged poll (two load-pairs in flight, vmcnt(2) alternating checks).
__global__ __launch_bounds__(384) void k_rec(
    const u16* __restrict__ xg,    // [16384][3072] bf16, m = seq*512 + t
    const u16* __restrict__ Whp,   // [32][6][24][64][8] packed bf16
    const float* __restrict__ bias,
    int* hbuf,                     // [8 groups][2][3072] tagged dwords (zeroed)
    u16* __restrict__ hout_bf,     // layer 0 out (bf16) or null
    float* __restrict__ hout_f,    // layer 1 out (fp32) or null
    int layer) {
  __shared__ __align__(16) int hlds[2][4 * 400];  // double-buffered h_{t-1}[4 seq][768]

  const int wid = blockIdx.x, g = wid & 7, w = wid >> 3;
  const int tid = threadIdx.x, lane = tid & 63, wv = tid >> 6;

  // ---- Wh fragments -> registers (static indices) ----
  bf16x8 bregE[12], bregO[12];
  {
    const u16* bp = Whp + (((size_t)(w * 6 + wv) * 24) * 64 + lane) * 8;
#pragma unroll
    for (int kk = 0; kk < 12; ++kk) {
      bregE[kk] = *(const bf16x8*)(bp + (size_t)(2 * kk) * 512);
      bregO[kk] = *(const bf16x8*)(bp + (size_t)(2 * kk + 1) * 512);
    }
  }

  // ---- cell role: lanes with (lane&15)<4 own cell (seq r = lane&3, unit vi = lane>>4) ----
  const bool cellt = (lane & 15) < 4;
  const int vi = lane >> 4, r = lane & 3;
  const int unit = w * 24 + wv * 4 + vi;
  const int seq = g * 4 + r;
  float bv0 = 0, bv1 = 0, bv2 = 0, bv3 = 0, xv0 = 0, xv1 = 0, xv2 = 0, xv3 = 0;
  if (cellt) {
    bv0 = bias[unit]; bv1 = bias[768 + unit]; bv2 = bias[1536 + unit]; bv3 = bias[2304 + unit];
    const u16* xr = xg + (size_t)seq * 512 * 3072;
    xv0 = bf2f(xr[unit]); xv1 = bf2f(xr[768 + unit]);
    xv2 = bf2f(xr[1536 + unit]); xv3 = bf2f(xr[2304 + unit]);
  }
  float cst = 0.f;
  const int sl = (lane & 15) < 4 ? (lane & 15) : 3;      // B-frag row (pad rows clamped)
  const int abase = sl * 400 + (lane >> 4) * 4;          // B-frag dword base within buffer
  const int c = tid;                                     // poll chunk id (8 dwords)
  const int hrow = c / 96, hcol = (c % 96) * 4;          // staged int4 slot
  int guard = 0;

  __syncthreads();

  for (int t = 0; t < 512; ++t) {
    int* hb = hlds[t & 1];
    // ---- 2-deep pipelined poll+fetch of tagged h_{t-1} ----
    const int expect = t;  // tag written by step t-1 producers (t=0: zeroed buffer)
    int* src = hbuf + (size_t)(g * 2 + (t & 1)) * 3072;
    const int* p0 = src + 8 * c;
    const int* p1 = src + 8 * c + 4;
    i32x4 vA0, vA1, vB0, vB1, v0, v1;
    asm volatile("global_load_dwordx4 %0, %4, off sc0 sc1\n\t"
                 "global_load_dwordx4 %1, %5, off sc0 sc1\n\t"
                 "global_load_dwordx4 %2, %4, off sc0 sc1\n\t"
                 "global_load_dwordx4 %3, %5, off sc0 sc1"
                 : "=&v"(vA0), "=&v"(vA1), "=&v"(vB0), "=&v"(vB1)
                 : "v"(p0), "v"(p1) : "memory");
    for (;;) {
      // wait until pair A landed ("+v" creates the data dep that orders the check after the wait)
      asm volatile("s_waitcnt vmcnt(2)" : "+v"(vA0), "+v"(vA1) :: "memory");
      if (tags_ok(vA0, vA1, expect)) {
        asm volatile("s_waitcnt vmcnt(0)" : "+v"(vA0), "+v"(vA1) :: "memory");
        v0 = vA0; v1 = vA1; break;
      }
      asm volatile("global_load_dwordx4 %0, %2, off sc0 sc1\n\t"
                   "global_load_dwordx4 %1, %3, off sc0 sc1"
                   : "=&v"(vA0), "=&v"(vA1) : "v"(p0), "v"(p1) : "memory");
      asm volatile("s_waitcnt vmcnt(2)" : "+v"(vB0), "+v"(vB1) :: "memory");
      if (tags_ok(vB0, vB1, expect)) {
        asm volatile("s_waitcnt vmcnt(0)" : "+v"(vB0), "+v"(vB1) :: "memory");
        v0 = vB0; v1 = vB1; break;
      }
      asm volatile("global_load_dwordx4 %0, %2, off sc0 sc1\n\t"
                   "global_load_dwordx4 %1, %3, off sc0 sc1"
                   : "=&v"(vB0), "=&v"(vB1) : "v"(p0), "v"(p1) : "memory");
      if ((guard += 2) > (1 << 22)) {
        asm volatile("s_waitcnt vmcnt(0)" : "+v"(vA0), "+v"(vA1) :: "memory");
        v0 = vA0; v1 = vA1; break;
      }
    }
    // stage packed bf16 pairs into hlds[t&1]
    {
      int4 pk;
      pk.x = (int)(((unsigned)v0[0] >> 16) | ((unsigned)v0[1] & 0xffff0000u));
      pk.y = (int)(((unsigned)v0[2] >> 16) | ((unsigned)v0[3] & 0xffff0000u));
      pk.z = (int)(((unsigned)v1[0] >> 16) | ((unsigned)v1[1] & 0xffff0000u));
      pk.w = (int)(((unsigned)v1[2] >> 16) | ((unsigned)v1[3] & 0xffff0000u));
      *(int4*)&hb[hrow * 400 + hcol] = pk;
    }
    __syncthreads();  // hlds[t&1] ready (also fences next step's staging vs MFMA(t-1))

    // ---- MFMA (swapped): D[cc][seq] = W(A) x h(B), 4 independent chains of 6 ----
    f32x4 a0 = {0, 0, 0, 0}, a1 = {0, 0, 0, 0}, a2 = {0, 0, 0, 0}, a3 = {0, 0, 0, 0};
#pragma unroll
    for (int kk = 0; kk < 12; kk += 2) {
      bf16x8 e0 = *(const bf16x8*)(hb + abase + (2 * kk) * 16);
      bf16x8 o0 = *(const bf16x8*)(hb + abase + (2 * kk + 1) * 16);
      bf16x8 e1 = *(const bf16x8*)(hb + abase + (2 * kk + 2) * 16);
      bf16x8 o1 = *(const bf16x8*)(hb + abase + (2 * kk + 3) * 16);
      a0 = __builtin_amdgcn_mfma_f32_16x16x32_bf16(bregE[kk], e0, a0, 0, 0, 0);
      a1 = __builtin_amdgcn_mfma_f32_16x16x32_bf16(bregO[kk], o0, a1, 0, 0, 0);
      a2 = __builtin_amdgcn_mfma_f32_16x16x32_bf16(bregE[kk + 1], e1, a2, 0, 0, 0);
      a3 = __builtin_amdgcn_mfma_f32_16x16x32_bf16(bregO[kk + 1], o1, a3, 0, 0, 0);
    }
    a0 = (a0 + a2) + (a1 + a3);
    // D layout: row = cc = (lane>>4)*4 + reg, col = seq = lane&15
    // -> lane 16*vi + r holds gates q=0..3 (i,f,g,o) of cell (seq r, unit vi) in a0[0..3]

    if (cellt) {
      float p0g = xv0 + a0[0] + bv0;
      float p1g = xv1 + a0[1] + bv1;
      float p2g = xv2 + a0[2] + bv2;
      float p3g = xv3 + a0[3] + bv3;
      float ig = sigm(p0g), fg = sigm(p1g), gg = tanh_f(p2g), og = sigm(p3g);
      cst = fg * cst + ig * gg;
      float h = og * tanh_f(cst);
      // publish tagged h (fire-and-forget; dword atomicity makes it self-validating)
      int* dst = hbuf + (size_t)(g * 2 + ((t + 1) & 1)) * 3072 + r * 768 + unit;
      int val = (int)(((unsigned)f2bf(h) << 16) | (unsigned)(t + 1));
      __hip_atomic_store(dst, val, __ATOMIC_RELAXED, AGENT);
      // off the critical path: output store + next-step xg prefetch
      size_t o = ((size_t)seq * 512 + t) * 768 + unit;
      if (layer == 0) hout_bf[o] = f2bf(h); else hout_f[o] = h;
      if (t + 1 < 512) {
        const u16* xr = xg + ((size_t)seq * 512 + t + 1) * 3072;
        xv0 = bf2f(xr[unit]); xv1 = bf2f(xr[768 + unit]);
        xv2 = bf2f(xr[1536 + unit]); xv3 = bf2f(xr[2304 + unit]);
      }
    }
  }
}

// ---------- LayerNorm (in-place safe) ----------
__global__ __launch_bounds__(256) void k_ln(const float* __restrict__ in, const float* __restrict__ sc,
                                            const float* __restrict__ bi, float* __restrict__ out) {
  const int row = blockIdx.x, tid = threadIdx.x;
  const float* x = in + (size_t)row * 768;
  float v0 = x[tid], v1 = x[tid + 256], v2 = x[tid + 512];
  float s = v0 + v1 + v2;
  float s2 = v0 * v0 + v1 * v1 + v2 * v2;
#pragma unroll
  for (int off = 32; off >= 1; off >>= 1) {
    s += __shfl_xor(s, off);
    s2 += __shfl_xor(s2, off);
  }
  __shared__ float red[8];
  const int wv = tid >> 6;
  if ((tid & 63) == 0) { red[wv] = s; red[4 + wv] = s2; }
  __syncthreads();
  s = red[0] + red[1] + red[2] + red[3];
  s2 = red[4] + red[5] + red[6] + red[7];
  float mean = s * (1.f / 768.f);
  float var = s2 * (1.f / 768.f) - mean * mean;
  float rs = rsqrtf(var + 1e-6f);
  float* o = out + (size_t)row * 768;
  o[tid] = (v0 - mean) * rs * sc[tid] + bi[tid];
  o[tid + 256] = (v1 - mean) * rs * sc[tid + 256] + bi[tid + 256];
  o[tid + 512] = (v2 - mean) * rs * sc[tid + 512] + bi[tid + 512];
}

extern "C" void kernel_launch(void* const* d_in, const int* in_sizes, int n_in,
                              void* d_out, int out_size, void* d_ws, size_t ws_size,
                              hipStream_t stream) {
  const float* x   = (const float*)d_in[0];
  const float* Wx0 = (const float*)d_in[1];
  const float* Wh0 = (const float*)d_in[2];
  const float* b0  = (const float*)d_in[3];
  const float* Wx1 = (const float*)d_in[4];
  const float* Wh1 = (const float*)d_in[5];
  const float* b1  = (const float*)d_in[6];
  const float* lns = (const float*)d_in[7];
  const float* lnb = (const float*)d_in[8];
  float* out = (float*)d_out;

  char* p = (char*)d_ws;
  auto alloc = [&](size_t bytes) {
    char* r = p;
    p += (bytes + 255) & ~(size_t)255;
    return r;
  };
  u16* xg    = (u16*)alloc(16384ull * 3072 * 2);
  u16* xbf   = (u16*)alloc(16384ull * 768 * 2);
  u16* h0bf  = (u16*)alloc(16384ull * 768 * 2);
  u16* Wxp0  = (u16*)alloc(2359296ull * 2);
  u16* Wxp1  = (u16*)alloc(2359296ull * 2);
  u16* Whp0  = (u16*)alloc(2359296ull * 2);
  u16* Whp1  = (u16*)alloc(2359296ull * 2);
  char* sync0 = alloc(196608ull * 2);   // hbuf0, hbuf1 (tagged dwords)
  int* hbuf0 = (int*)sync0;
  int* hbuf1 = (int*)(sync0 + 196608);

  if ((size_t)(p - (char*)d_ws) > ws_size) {
    fprintf(stderr, "kernel_launch: ws too small: need %zu have %zu\n",
            (size_t)(p - (char*)d_ws), ws_size);
    return;
  }

  hipMemsetAsync(sync0, 0, 196608ull * 2, stream);
  k_cvt<<<12288, 256, 0, stream>>>(x, xbf, 3145728);
  k_pack_wx<<<9216, 256, 0, stream>>>(Wx0, Wxp0);
  k_pack_wx<<<9216, 256, 0, stream>>>(Wx1, Wxp1);
  k_pack_wh<<<9216, 256, 0, stream>>>(Wh0, Whp0);
  k_pack_wh<<<9216, 256, 0, stream>>>(Wh1, Whp1);

  k_gemm<<<3072, 256, 0, stream>>>(xbf, Wxp0, xg);
  k_rec<<<256, 384, 0, stream>>>(xg, Whp0, b0, hbuf0, h0bf, nullptr, 0);
  k_gemm<<<3072, 256, 0, stream>>>(h0bf, Wxp1, xg);
  k_rec<<<256, 384, 0, stream>>>(xg, Whp1, b1, hbuf1, nullptr, (float*)d_out, 1);
  k_ln<<<16384, 256, 0, stream>>>((const float*)d_out, lns, lnb, out);
}

// Round 12
// 2141.077 us; speedup vs baseline: 35.0915x; 1.4711x over previous
//
#include <hip/hip_runtime.h>
#include <stdint.h>
#include <cstdio>

typedef unsigned short u16;
typedef __attribute__((ext_vector_type(8))) __bf16 bf16x8;
typedef __attribute__((ext_vector_type(4))) float f32x4;
typedef __attribute__((ext_vector_type(4))) int i32x4;

#define AGENT __HIP_MEMORY_SCOPE_AGENT

__device__ __forceinline__ float bf2f(u16 u) {
  unsigned int x = ((unsigned int)u) << 16;
  return __builtin_bit_cast(float, x);
}
__device__ __forceinline__ u16 f2bf(float f) {
  unsigned int x = __builtin_bit_cast(unsigned int, f);
  unsigned int r = (x + 0x7fffu + ((x >> 16) & 1u)) >> 16;
  return (u16)r;
}
__device__ __forceinline__ float sigm(float x) { return 1.f / (1.f + __expf(-x)); }
__device__ __forceinline__ float tanh_f(float x) { return 1.f - 2.f / (__expf(2.f * x) + 1.f); }

// ---------- fp32 -> bf16 convert (x) ----------
__global__ __launch_bounds__(256) void k_cvt(const float* __restrict__ in, u16* __restrict__ out, int n4) {
  int i = blockIdx.x * 256 + threadIdx.x;
  if (i >= n4) return;
  float4 f = ((const float4*)in)[i];
  ushort4 o;
  o.x = f2bf(f.x); o.y = f2bf(f.y); o.z = f2bf(f.z); o.w = f2bf(f.w);
  ((ushort4*)out)[i] = o;
}

// ---------- pack Wx [768][3072] -> B-fragment order [nt=192][kt=24][lane=64][j=8] ----------
__global__ __launch_bounds__(256) void k_pack_wx(const float* __restrict__ Wx, u16* __restrict__ Bp) {
  int idx = blockIdx.x * 256 + threadIdx.x;
  if (idx >= 2359296) return;
  int j = idx & 7;
  int l = (idx >> 3) & 63;
  int t = idx >> 9;          // nt*24 + kt
  int kt = t % 24, nt = t / 24;
  int k = kt * 32 + (l >> 4) * 8 + j;
  int n = nt * 16 + (l & 15);
  Bp[idx] = f2bf(Wx[(size_t)k * 3072 + n]);
}

// ---------- pack Wh -> per-member slices [w=32][nt=6][kt=24][lane=64][j=8] ----------
// col order within 16-col tile: cc = 4*vi + q (vi = unit-in-wave 0..3, q = gate 0..3)
// Serves as the A-operand (rows = cc) of the swapped MFMA.
__global__ __launch_bounds__(256) void k_pack_wh(const float* __restrict__ Wh, u16* __restrict__ Wp) {
  int idx = blockIdx.x * 256 + threadIdx.x;
  if (idx >= 2359296) return;
  int j = idx & 7;
  int l = (idx >> 3) & 63;
  int t = idx >> 9;          // w*144 + nt*24 + kt
  int kt = t % 24;
  int tmp = t / 24;          // w*6 + nt
  int nt = tmp % 6, w = tmp / 6;
  int k = kt * 32 + (l >> 4) * 8 + j;
  int cc = l & 15;
  int vi = cc >> 2, q = cc & 3;
  int gcol = q * 768 + w * 24 + nt * 4 + vi;
  Wp[idx] = f2bf(Wh[(size_t)k * 3072 + gcol]);
}

// ---------- GEMM: C[16384][3072] bf16 = A[16384][768] bf16 @ Bp(packed) ----------
__global__ __launch_bounds__(256, 2) void k_gemm(const u16* __restrict__ A, const u16* __restrict__ Bp,
                                                 u16* __restrict__ C) {
  const int bid = blockIdx.x;
  const int bm = bid & 127, bn = bid >> 7;   // 128 x 24
  const int tid = threadIdx.x, lane = tid & 63, wv = tid >> 6;
  const int wm = wv >> 1, wn = wv & 1;
  const int row0 = bm * 128 + wm * 64;
  const int col0 = bn * 128 + wn * 64;
  const int rlo = lane & 15, rhi = lane >> 4;
  f32x4 acc[4][4] = {};
  const u16* Ab = A + (size_t)(row0 + rlo) * 768 + rhi * 8;
  const u16* Bb = Bp + ((size_t)(bn * 8 + wn * 4) * 24 * 64 + lane) * 8;
#pragma unroll 2
  for (int kt = 0; kt < 24; ++kt) {
    bf16x8 a[4], b[4];
#pragma unroll
    for (int i = 0; i < 4; ++i) a[i] = *(const bf16x8*)(Ab + (size_t)i * 16 * 768 + kt * 32);
#pragma unroll
    for (int j = 0; j < 4; ++j) b[j] = *(const bf16x8*)(Bb + (size_t)j * 24 * 64 * 8 + (size_t)kt * 64 * 8);
#pragma unroll
    for (int i = 0; i < 4; ++i)
#pragma unroll
      for (int j = 0; j < 4; ++j)
        acc[i][j] = __builtin_amdgcn_mfma_f32_16x16x32_bf16(a[i], b[j], acc[i][j], 0, 0, 0);
  }
#pragma unroll
  for (int i = 0; i < 4; ++i)
#pragma unroll
    for (int j = 0; j < 4; ++j)
#pragma unroll
      for (int r = 0; r < 4; ++r) {
        int row = row0 + i * 16 + rhi * 4 + r;
        int col = col0 + j * 16 + rlo;
        C[(size_t)row * 3072 + col] = f2bf(acc[i][j][r]);
      }
}

// ---------- persistent LSTM recurrence ----------
// 256 WGs x 384 threads (6 waves) — R6-proven base (900 µs). Logical groups: g = wid&7
// (4 seqs), member w = wid>>3 (24 units). Wave wv owns one 16-col tile = 4 gates x 4 units.
// Per step: merged poll+fetch of tagged h_{t-1} (the full load IS the poll, 1 LLC RT) ->
// B_A -> stage hlds -> B3 -> SWAPPED MFMA D = W(A) x h(B) -> D[cc][seq]: lane 16*vi + r
// holds all 4 gates (regs q=0..3) of cell (seq r, unit vi) -> cell math straight from acc
// (no LDS transpose) -> fire-and-forget tagged publish (bf16_h<<16 | t+1), parity dbuf.
__global__ __launch_bounds__(384) void k_rec(
    const u16* __restrict__ xg,    // [16384][3072] bf16, m = seq*512 + t
    const u16* __restrict__ Whp,   // [32][6][24][64][8] packed bf16
    const float* __restrict__ bias,
    int* hbuf,                     // [8 groups][2][3072] tagged dwords (zeroed)
    u16* __restrict__ hout_bf,     // layer 0 out (bf16) or null
    float* __restrict__ hout_f,    // layer 1 out (fp32) or null
    int layer) {
  __shared__ __align__(16) int hlds[4 * 400];   // h_{t-1}[4 seq][768] bf16, rows padded to 400 dw

  const int wid = blockIdx.x, g = wid & 7, w = wid >> 3;
  const int tid = threadIdx.x, lane = tid & 63, wv = tid >> 6;

  // ---- Wh fragments -> registers (static indices) ----
  bf16x8 bregE[12], bregO[12];
  {
    const u16* bp = Whp + (((size_t)(w * 6 + wv) * 24) * 64 + lane) * 8;
#pragma unroll
    for (int kk = 0; kk < 12; ++kk) {
      bregE[kk] = *(const bf16x8*)(bp + (size_t)(2 * kk) * 512);
      bregO[kk] = *(const bf16x8*)(bp + (size_t)(2 * kk + 1) * 512);
    }
  }

  // ---- cell role: lane = 16*vi + r owns cell (seq r, unit vi) ----
  const bool cellt = (lane & 15) < 4;
  const int vi = lane >> 4, r = lane & 3;
  const int unit = w * 24 + wv * 4 + vi;
  const int seq = g * 4 + r;
  float bv0 = 0, bv1 = 0, bv2 = 0, bv3 = 0, xv0 = 0, xv1 = 0, xv2 = 0, xv3 = 0;
  if (cellt) {
    bv0 = bias[unit]; bv1 = bias[768 + unit]; bv2 = bias[1536 + unit]; bv3 = bias[2304 + unit];
    const u16* xr = xg + (size_t)seq * 512 * 3072;
    xv0 = bf2f(xr[unit]); xv1 = bf2f(xr[768 + unit]);
    xv2 = bf2f(xr[1536 + unit]); xv3 = bf2f(xr[2304 + unit]);
  }
  float cst = 0.f;
  const int sl = (lane & 15) < 4 ? (lane & 15) : 3;      // h-frag row (pad rows clamped)
  const int abase = sl * 400 + (lane >> 4) * 4;          // h-frag dword base in hlds
  // poll/stage role: thread tid handles 8 tagged dwords
  const int c = tid;                                     // 0..383
  const int hrow = c / 96, hcol = (c % 96) * 4;          // packed int4 slot in hlds
  int guard = 0;

  __syncthreads();

  for (int t = 0; t < 512; ++t) {
    // ---- merged poll+fetch of h_{t-1}: full tagged load IS the poll (1 RT) ----
    const int expect = t;  // tag written by step t-1 producers (t=0: zeroed buffer)
    int* src = hbuf + (size_t)(g * 2 + (t & 1)) * 3072;
    const int* p0 = src + 8 * c;
    const int* p1 = src + 8 * c + 4;
    i32x4 v0, v1;
    for (;;) {
      asm volatile("global_load_dwordx4 %0, %2, off sc0 sc1\n\t"
                   "global_load_dwordx4 %1, %3, off sc0 sc1\n\t"
                   "s_waitcnt vmcnt(0)"
                   : "=&v"(v0), "=&v"(v1)
                   : "v"(p0), "v"(p1)
                   : "memory");
      bool ok = true;
#pragma unroll
      for (int j = 0; j < 4; ++j)
        ok = ok && ((v0[j] & 0xffff) == expect) && ((v1[j] & 0xffff) == expect);
      if (ok || ++guard > (1 << 22)) break;
    }
    __syncthreads();  // B_A: all waves done reading hlds (MFMA of t-1)

    // stage packed bf16 pairs into hlds
    {
      int4 pk;
      pk.x = (int)(((unsigned)v0[0] >> 16) | ((unsigned)v0[1] & 0xffff0000u));
      pk.y = (int)(((unsigned)v0[2] >> 16) | ((unsigned)v0[3] & 0xffff0000u));
      pk.z = (int)(((unsigned)v1[0] >> 16) | ((unsigned)v1[1] & 0xffff0000u));
      pk.w = (int)(((unsigned)v1[2] >> 16) | ((unsigned)v1[3] & 0xffff0000u));
      *(int4*)&hlds[hrow * 400 + hcol] = pk;
    }
    __syncthreads();  // B3: hlds ready

    // ---- MFMA (swapped): D[cc][seq] = W(A) x h(B), kt-parity 2 chains ----
    f32x4 a0 = {0, 0, 0, 0}, a1 = {0, 0, 0, 0};
#pragma unroll
    for (int kk = 0; kk < 12; ++kk) {
      bf16x8 afe = *(const bf16x8*)(hlds + abase + (2 * kk) * 16);
      bf16x8 afo = *(const bf16x8*)(hlds + abase + (2 * kk + 1) * 16);
      a0 = __builtin_amdgcn_mfma_f32_16x16x32_bf16(bregE[kk], afe, a0, 0, 0, 0);
      a1 = __builtin_amdgcn_mfma_f32_16x16x32_bf16(bregO[kk], afo, a1, 0, 0, 0);
    }
    a0 += a1;
    // D layout: row = cc = (lane>>4)*4 + reg, col = seq = lane&15
    // -> lane 16*vi + r holds gates q=0..3 (i,f,g,o) of cell (seq r, unit vi) in a0[0..3]

    if (cellt) {
      float p0g = xv0 + a0[0] + bv0;
      float p1g = xv1 + a0[1] + bv1;
      float p2g = xv2 + a0[2] + bv2;
      float p3g = xv3 + a0[3] + bv3;
      float ig = sigm(p0g), fg = sigm(p1g), gg = tanh_f(p2g), og = sigm(p3g);
      cst = fg * cst + ig * gg;
      float h = og * tanh_f(cst);
      // publish tagged h (fire-and-forget; dword atomicity makes it self-validating)
      int* dst = hbuf + (size_t)(g * 2 + ((t + 1) & 1)) * 3072 + r * 768 + unit;
      int val = (int)(((unsigned)f2bf(h) << 16) | (unsigned)(t + 1));
      __hip_atomic_store(dst, val, __ATOMIC_RELAXED, AGENT);
      // off the critical path: output store + next-step xg prefetch
      size_t o = ((size_t)seq * 512 + t) * 768 + unit;
      if (layer == 0) hout_bf[o] = f2bf(h); else hout_f[o] = h;
      if (t + 1 < 512) {
        const u16* xr = xg + ((size_t)seq * 512 + t + 1) * 3072;
        xv0 = bf2f(xr[unit]); xv1 = bf2f(xr[768 + unit]);
        xv2 = bf2f(xr[1536 + unit]); xv3 = bf2f(xr[2304 + unit]);
      }
    }
  }
}

// ---------- LayerNorm (in-place safe) ----------
__global__ __launch_bounds__(256) void k_ln(const float* __restrict__ in, const float* __restrict__ sc,
                                            const float* __restrict__ bi, float* __restrict__ out) {
  const int row = blockIdx.x, tid = threadIdx.x;
  const float* x = in + (size_t)row * 768;
  float v0 = x[tid], v1 = x[tid + 256], v2 = x[tid + 512];
  float s = v0 + v1 + v2;
  float s2 = v0 * v0 + v1 * v1 + v2 * v2;
#pragma unroll
  for (int off = 32; off >= 1; off >>= 1) {
    s += __shfl_xor(s, off);
    s2 += __shfl_xor(s2, off);
  }
  __shared__ float red[8];
  const int wv = tid >> 6;
  if ((tid & 63) == 0) { red[wv] = s; red[4 + wv] = s2; }
  __syncthreads();
  s = red[0] + red[1] + red[2] + red[3];
  s2 = red[4] + red[5] + red[6] + red[7];
  float mean = s * (1.f / 768.f);
  float var = s2 * (1.f / 768.f) - mean * mean;
  float rs = rsqrtf(var + 1e-6f);
  float* o = out + (size_t)row * 768;
  o[tid] = (v0 - mean) * rs * sc[tid] + bi[tid];
  o[tid + 256] = (v1 - mean) * rs * sc[tid + 256] + bi[tid + 256];
  o[tid + 512] = (v2 - mean) * rs * sc[tid + 512] + bi[tid + 512];
}

extern "C" void kernel_launch(void* const* d_in, const int* in_sizes, int n_in,
                              void* d_out, int out_size, void* d_ws, size_t ws_size,
                              hipStream_t stream) {
  const float* x   = (const float*)d_in[0];
  const float* Wx0 = (const float*)d_in[1];
  const float* Wh0 = (const float*)d_in[2];
  const float* b0  = (const float*)d_in[3];
  const float* Wx1 = (const float*)d_in[4];
  const float* Wh1 = (const float*)d_in[5];
  const float* b1  = (const float*)d_in[6];
  const float* lns = (const float*)d_in[7];
  const float* lnb = (const float*)d_in[8];
  float* out = (float*)d_out;

  char* p = (char*)d_ws;
  auto alloc = [&](size_t bytes) {
    char* r = p;
    p += (bytes + 255) & ~(size_t)255;
    return r;
  };
  u16* xg    = (u16*)alloc(16384ull * 3072 * 2);
  u16* xbf   = (u16*)alloc(16384ull * 768 * 2);
  u16* h0bf  = (u16*)alloc(16384ull * 768 * 2);
  u16* Wxp0  = (u16*)alloc(2359296ull * 2);
  u16* Wxp1  = (u16*)alloc(2359296ull * 2);
  u16* Whp0  = (u16*)alloc(2359296ull * 2);
  u16* Whp1  = (u16*)alloc(2359296ull * 2);
  char* sync0 = alloc(196608ull * 2);   // hbuf0, hbuf1 (tagged dwords)
  int* hbuf0 = (int*)sync0;
  int* hbuf1 = (int*)(sync0 + 196608);

  if ((size_t)(p - (char*)d_ws) > ws_size) {
    fprintf(stderr, "kernel_launch: ws too small: need %zu have %zu\n",
            (size_t)(p - (char*)d_ws), ws_size);
    return;
  }

  hipMemsetAsync(sync0, 0, 196608ull * 2, stream);
  k_cvt<<<12288, 256, 0, stream>>>(x, xbf, 3145728);
  k_pack_wx<<<9216, 256, 0, stream>>>(Wx0, Wxp0);
  k_pack_wx<<<9216, 256, 0, stream>>>(Wx1, Wxp1);
  k_pack_wh<<<9216, 256, 0, stream>>>(Wh0, Whp0);
  k_pack_wh<<<9216, 256, 0, stream>>>(Wh1, Whp1);

  k_gemm<<<3072, 256, 0, stream>>>(xbf, Wxp0, xg);
  k_rec<<<256, 384, 0, stream>>>(xg, Whp0, b0, hbuf0, h0bf, nullptr, 0);
  k_gemm<<<3072, 256, 0, stream>>>(h0bf, Wxp1, xg);
  k_rec<<<256, 384, 0, stream>>>(xg, Whp1, b1, hbuf1, nullptr, (float*)d_out, 1);
  k_ln<<<16384, 256, 0, stream>>>((const float*)d_out, lns, lnb, out);
}